// Round 3
// baseline (125.400 us; speedup 1.0000x reference)
//
#include <hip/hip_runtime.h>

// Problem: B=2, S=2048, D=512, H=8, dh=64.
// 3-kernel pipeline:
//   prep: Xh=bf16(X), Wqt=bf16(Wq^T), t[h]=Wh^T Wv
//   gemm: Qh = Xh @ Wq (bf16 MFMA, swizzled global_load_lds staging)
//         epilogue: n[b,h,s]=||Q_head|| (fp32 acc), y=Q_head.t[h], nmax via atomicMax
//   attn: out = sigmoid( softmax((2QQ^T - n_s - n_t)/8) @ y )
//         exact bound M_s = (2 n_s N - n_s - N)/8 -> no online rescale needed

typedef __attribute__((ext_vector_type(8))) short bf16x8;
typedef __attribute__((ext_vector_type(4))) float f32x4;

#if __has_builtin(__builtin_amdgcn_exp2f)
#define EXP2F(x) __builtin_amdgcn_exp2f(x)
#else
#define EXP2F(x) exp2f(x)
#endif

#define LOG2E 1.44269504088896341f

__device__ inline unsigned int f2b(float f) {  // fp32 -> bf16 bits, RNE
    unsigned int u = __float_as_uint(f);
    return (u + 0x7fffu + ((u >> 16) & 1u)) >> 16;
}

// async global->LDS, 16B per lane; LDS dest = wave-uniform base + lane*16
__device__ __forceinline__ void glds16(const unsigned short* g, unsigned short* l) {
    __builtin_amdgcn_global_load_lds(
        (const __attribute__((address_space(1))) unsigned int*)g,
        (__attribute__((address_space(3))) unsigned int*)l, 16, 0, 0);
}

// swizzled LDS tile: row stride 64 bf16 (128B), chunk c (16B) at (c ^ (row&7))
// staged by glds16 groups of 8 rows: lane l -> row l>>3, global chunk (l&7)^(l>>3)
#define SWZ(row, c) ((row) * 64 + (((c) ^ ((row) & 7)) * 8))

// ---- prep: blocks [0,1024) castX, [1024,1280) transpose-cast Wq, [1280,1288) t ----
__global__ __launch_bounds__(256) void prep_k(const float* __restrict__ X,
                                              const float* __restrict__ Wq,
                                              const float* __restrict__ Wv,
                                              unsigned short* __restrict__ Xh,
                                              unsigned short* __restrict__ Wqt,
                                              float* __restrict__ t_out) {
    __shared__ float sh[32 * 33];
    int blk = blockIdx.x;
    int tid = threadIdx.x;
    if (blk < 1024) {
        int base = (blk * 256 + tid) * 8;
        float4 a = *(const float4*)&X[base];
        float4 c = *(const float4*)&X[base + 4];
        uint4 o;
        o.x = f2b(a.x) | (f2b(a.y) << 16);
        o.y = f2b(a.z) | (f2b(a.w) << 16);
        o.z = f2b(c.x) | (f2b(c.y) << 16);
        o.w = f2b(c.z) | (f2b(c.w) << 16);
        *(uint4*)&Xh[base] = o;
    } else if (blk < 1280) {
        int bidx = blk - 1024;
        int k0 = (bidx >> 4) * 32, n0 = (bidx & 15) * 32;
        int r = tid >> 3, c4 = (tid & 7) * 4;
        float4 v = *(const float4*)&Wq[(k0 + r) * 512 + n0 + c4];
        sh[(c4 + 0) * 33 + r] = v.x;
        sh[(c4 + 1) * 33 + r] = v.y;
        sh[(c4 + 2) * 33 + r] = v.z;
        sh[(c4 + 3) * 33 + r] = v.w;
        __syncthreads();
        float w0 = sh[r * 33 + c4 + 0], w1 = sh[r * 33 + c4 + 1];
        float w2 = sh[r * 33 + c4 + 2], w3 = sh[r * 33 + c4 + 3];
        uint2 o;
        o.x = f2b(w0) | (f2b(w1) << 16);
        o.y = f2b(w2) | (f2b(w3) << 16);
        *(uint2*)&Wqt[(n0 + r) * 512 + k0 + c4] = o;
    } else {
        int h = blk - 1280;
        int rr = tid >> 6, c = tid & 63;
        float acc = 0.f;
        for (int j = 0; j < 128; ++j) {
            int d = rr + 4 * j;
            acc = fmaf(Wq[d * 512 + h * 64 + c], Wv[d], acc);
        }
        sh[rr * 64 + c] = acc;
        __syncthreads();
        if (rr == 0)
            t_out[h * 64 + c] = sh[c] + sh[64 + c] + sh[128 + c] + sh[192 + c];
    }
}

// ---- Qh = Xh @ Wq via MFMA; epilogue computes n, y, nmax ----
__global__ __launch_bounds__(256) void gemm_k(const unsigned short* __restrict__ Xh,
                                              const unsigned short* __restrict__ Wqt,
                                              const float* __restrict__ t_in,
                                              unsigned short* __restrict__ Qh,
                                              float* __restrict__ n_out,
                                              float* __restrict__ y_out,
                                              float* __restrict__ nmax) {
    __shared__ __align__(16) unsigned short As[64 * 64];
    __shared__ __align__(16) unsigned short Bs[64 * 64];
    int tid = threadIdx.x;
    int h = blockIdx.x;
    int m0 = blockIdx.y * 64, n0 = h * 64;
    int w = tid >> 6, lane = tid & 63;
    int tt = lane & 15, quad = lane >> 4;
    int srow = lane >> 3;                       // staging row within 8-row group
    int schunk = ((lane & 7) ^ srow) * 8;       // swizzled global chunk (bf16 elems)
    int arow = w * 16 + tt;
    f32x4 acc[4] = {{0.f,0.f,0.f,0.f},{0.f,0.f,0.f,0.f},{0.f,0.f,0.f,0.f},{0.f,0.f,0.f,0.f}};
    for (int k0 = 0; k0 < 512; k0 += 64) {
        __syncthreads();
        #pragma unroll
        for (int q = 0; q < 2; ++q) {
            int r0 = w * 16 + q * 8;
            glds16(&Xh[(m0 + r0 + srow) * 512 + k0 + schunk], &As[r0 * 64]);
            glds16(&Wqt[(n0 + r0 + srow) * 512 + k0 + schunk], &Bs[r0 * 64]);
        }
        __syncthreads();
        bf16x8 a0 = *(const bf16x8*)&As[SWZ(arow, quad)];
        bf16x8 a1 = *(const bf16x8*)&As[SWZ(arow, quad + 4)];
        #pragma unroll
        for (int ct = 0; ct < 4; ++ct) {
            int brow = ct * 16 + tt;
            bf16x8 b0 = *(const bf16x8*)&Bs[SWZ(brow, quad)];
            bf16x8 b1 = *(const bf16x8*)&Bs[SWZ(brow, quad + 4)];
            acc[ct] = __builtin_amdgcn_mfma_f32_16x16x32_bf16(a0, b0, acc[ct], 0, 0, 0);
            acc[ct] = __builtin_amdgcn_mfma_f32_16x16x32_bf16(a1, b1, acc[ct], 0, 0, 0);
        }
    }
    // epilogue: Qh store + n/y/nmax from fp32 acc
    float tv[4];
    #pragma unroll
    for (int ct = 0; ct < 4; ++ct) tv[ct] = t_in[h * 64 + ct * 16 + tt];
    float s2[4] = {0.f,0.f,0.f,0.f}, yp[4] = {0.f,0.f,0.f,0.f};
    #pragma unroll
    for (int ct = 0; ct < 4; ++ct)
        #pragma unroll
        for (int g = 0; g < 4; ++g) {
            float v = acc[ct][g];
            s2[g] = fmaf(v, v, s2[g]);
            yp[g] = fmaf(v, tv[ct], yp[g]);
            Qh[(m0 + w * 16 + quad * 4 + g) * 512 + n0 + ct * 16 + tt] =
                (unsigned short)f2b(v);
        }
    #pragma unroll
    for (int off = 1; off <= 8; off <<= 1)
        #pragma unroll
        for (int g = 0; g < 4; ++g) {
            s2[g] += __shfl_xor(s2[g], off);
            yp[g] += __shfl_xor(yp[g], off);
        }
    float nv[4], nloc = 0.f;
    #pragma unroll
    for (int g = 0; g < 4; ++g) {
        nv[g] = sqrtf(s2[g]);
        nloc = fmaxf(nloc, nv[g]);
    }
    int bb = m0 >> 11;
    if (tt == 0) {
        #pragma unroll
        for (int g = 0; g < 4; ++g) {
            int row = m0 + w * 16 + quad * 4 + g;
            int idx = ((bb * 8 + h) << 11) + (row & 2047);
            n_out[idx] = nv[g];
            y_out[idx] = yp[g];
        }
    }
    #pragma unroll
    for (int off = 1; off <= 32; off <<= 1)
        nloc = fmaxf(nloc, __shfl_xor(nloc, off));
    if (lane == 0)
        atomicMax((int*)&nmax[bb * 8 + h], __float_as_int(nloc));
}

// ---- attention: 64 query rows/block, t-chunks of 128; each wave owns 16 rows ----
// arg = 0.25*LOG2E*dots + rowc[s] + tq[t];  rowc = -0.125*LOG2E*N*(2 n_s - 1)
__global__ __launch_bounds__(256) void attn_k(const unsigned short* __restrict__ Qh,
                                              const float* __restrict__ n_in,
                                              const float* __restrict__ y_in,
                                              const float* __restrict__ nmax,
                                              float* __restrict__ out) {
    __shared__ __align__(16) unsigned short QsL[64 * 64];
    __shared__ __align__(16) unsigned short QtL[128 * 64];
    __shared__ float rowcL[64];
    __shared__ float tqL[128], ytL[128];

    int tid = threadIdx.x;
    int bh = blockIdx.x >> 5;          // 16 bh x 32 tiles
    int tile = blockIdx.x & 31;
    int s0 = tile * 64;
    int b = bh >> 3, h = bh & 7;
    int rowbase = (b * 2048) * 512 + h * 64;
    int w = tid >> 6, lane = tid & 63;
    int tt = lane & 15, quad = lane >> 4;
    int srow = lane >> 3;
    int schunk = ((lane & 7) ^ srow) * 8;

    #pragma unroll
    for (int q = 0; q < 2; ++q) {
        int r0 = w * 16 + q * 8;
        glds16(&Qh[rowbase + (s0 + r0 + srow) * 512 + schunk], &QsL[r0 * 64]);
    }
    float Nv = nmax[bh];
    if (tid < 64) {
        float ns = n_in[bh * 2048 + s0 + tid];
        rowcL[tid] = -0.125f * LOG2E * Nv * (2.f * ns - 1.f);
    }
    __syncthreads();

    int arow = w * 16 + tt;
    bf16x8 a0 = *(const bf16x8*)&QsL[SWZ(arow, quad)];
    bf16x8 a1 = *(const bf16x8*)&QsL[SWZ(arow, quad + 4)];
    float rc[4];
    #pragma unroll
    for (int g = 0; g < 4; ++g) rc[g] = rowcL[w * 16 + quad * 4 + g];
    f32x4 num = {0.f, 0.f, 0.f, 0.f}, den = {0.f, 0.f, 0.f, 0.f};

    for (int t0 = 0; t0 < 2048; t0 += 128) {
        __syncthreads();
        #pragma unroll
        for (int q = 0; q < 4; ++q) {
            int r0 = w * 32 + q * 8;
            glds16(&Qh[rowbase + (t0 + r0 + srow) * 512 + schunk], &QtL[r0 * 64]);
        }
        if (tid < 128)
            tqL[tid] = -0.125f * LOG2E * n_in[bh * 2048 + t0 + tid];
        else
            ytL[tid - 128] = y_in[bh * 2048 + t0 + tid - 128];
        __syncthreads();

        #pragma unroll
        for (int j = 0; j < 8; ++j) {
            int trow = j * 16 + tt;
            bf16x8 b0 = *(const bf16x8*)&QtL[SWZ(trow, quad)];
            bf16x8 b1 = *(const bf16x8*)&QtL[SWZ(trow, quad + 4)];
            f32x4 dot = {0.f, 0.f, 0.f, 0.f};
            dot = __builtin_amdgcn_mfma_f32_16x16x32_bf16(a0, b0, dot, 0, 0, 0);
            dot = __builtin_amdgcn_mfma_f32_16x16x32_bf16(a1, b1, dot, 0, 0, 0);
            float tqv = tqL[trow], yv = ytL[trow];
            #pragma unroll
            for (int g = 0; g < 4; ++g) {
                float arg = fmaf(0.25f * LOG2E, dot[g], rc[g] + tqv);
                float e = EXP2F(arg);
                num[g] = fmaf(e, yv, num[g]);
                den[g] += e;
            }
        }
    }

    #pragma unroll
    for (int off = 1; off <= 8; off <<= 1)
        #pragma unroll
        for (int g = 0; g < 4; ++g) {
            num[g] += __shfl_xor(num[g], off);
            den[g] += __shfl_xor(den[g], off);
        }
    if (tt == 0) {
        #pragma unroll
        for (int g = 0; g < 4; ++g) {
            int s = s0 + w * 16 + quad * 4 + g;
            float x = num[g] / den[g];
            out[bh * 2048 + s] = 1.0f / (1.0f + EXP2F(-x * LOG2E));
        }
    }
}

extern "C" void kernel_launch(void* const* d_in, const int* in_sizes, int n_in,
                              void* d_out, int out_size, void* d_ws, size_t ws_size,
                              hipStream_t stream) {
    const float* X  = (const float*)d_in[0];
    const float* Wq = (const float*)d_in[1];
    const float* Wv = (const float*)d_in[2];
    float* out = (float*)d_out;
    float* ws = (float*)d_ws;

    float* t_ws    = ws;                  // 512
    float* n_ws    = ws + 512;            // 32768
    float* y_ws    = ws + 33280;          // 32768
    float* nmax_ws = ws + 66048;          // 16
    unsigned short* Qh_ws  = (unsigned short*)(ws + 66064);   // 2M bf16
    unsigned short* Xh_ws  = Qh_ws + 2097152;                 // 2M bf16
    unsigned short* Wqt_ws = Xh_ws + 2097152;                 // 256K bf16

    prep_k<<<1288, 256, 0, stream>>>(X, Wq, Wv, Xh_ws, Wqt_ws, t_ws);
    gemm_k<<<dim3(8, 64), 256, 0, stream>>>(Xh_ws, Wqt_ws, t_ws, Qh_ws,
                                            n_ws, y_ws, nmax_ws);
    attn_k<<<512, 256, 0, stream>>>(Qh_ws, n_ws, y_ws, nmax_ws, out);
}

// Round 4
// 122.520 us; speedup vs baseline: 1.0235x; 1.0235x over previous
//
#include <hip/hip_runtime.h>

// Problem: B=2, S=2048, D=512, H=8, dh=64.
// 3-kernel pipeline:
//   prep: Xh=bf16(X), Wqt=bf16(Wq^T), t[h]=Wh^T Wv
//   gemm: Qh = Xh @ Wq (bf16 MFMA, swizzled global_load_lds staging)
//         epilogue: n[b,h,s]=||Q_head|| (fp32 acc), y=Q_head.t[h], nmax via atomicMax
//   attn: out = sigmoid( softmax((2QQ^T - n_s - n_t)/8) @ y )
//         exact bound M_s = (2 n_s N - n_s - N)/8 -> no online rescale needed
// R4: attn uses 512-thread blocks (8 waves) so 64-row tiles keep 4 waves/SIMD.

typedef __attribute__((ext_vector_type(8))) short bf16x8;
typedef __attribute__((ext_vector_type(4))) float f32x4;

#if __has_builtin(__builtin_amdgcn_exp2f)
#define EXP2F(x) __builtin_amdgcn_exp2f(x)
#else
#define EXP2F(x) exp2f(x)
#endif

#define LOG2E 1.44269504088896341f

__device__ inline unsigned int f2b(float f) {  // fp32 -> bf16 bits, RNE
    unsigned int u = __float_as_uint(f);
    return (u + 0x7fffu + ((u >> 16) & 1u)) >> 16;
}

// async global->LDS, 16B per lane; LDS dest = wave-uniform base + lane*16
__device__ __forceinline__ void glds16(const unsigned short* g, unsigned short* l) {
    __builtin_amdgcn_global_load_lds(
        (const __attribute__((address_space(1))) unsigned int*)g,
        (__attribute__((address_space(3))) unsigned int*)l, 16, 0, 0);
}

// swizzled LDS tile: row stride 64 bf16 (128B), chunk c (16B) at (c ^ (row&7))
#define SWZ(row, c) ((row) * 64 + (((c) ^ ((row) & 7)) * 8))

// ---- prep: blocks [0,1024) castX, [1024,1280) transpose-cast Wq, [1280,1288) t ----
__global__ __launch_bounds__(256) void prep_k(const float* __restrict__ X,
                                              const float* __restrict__ Wq,
                                              const float* __restrict__ Wv,
                                              unsigned short* __restrict__ Xh,
                                              unsigned short* __restrict__ Wqt,
                                              float* __restrict__ t_out) {
    __shared__ float sh[32 * 33];
    int blk = blockIdx.x;
    int tid = threadIdx.x;
    if (blk < 1024) {
        int base = (blk * 256 + tid) * 8;
        float4 a = *(const float4*)&X[base];
        float4 c = *(const float4*)&X[base + 4];
        uint4 o;
        o.x = f2b(a.x) | (f2b(a.y) << 16);
        o.y = f2b(a.z) | (f2b(a.w) << 16);
        o.z = f2b(c.x) | (f2b(c.y) << 16);
        o.w = f2b(c.z) | (f2b(c.w) << 16);
        *(uint4*)&Xh[base] = o;
    } else if (blk < 1280) {
        int bidx = blk - 1024;
        int k0 = (bidx >> 4) * 32, n0 = (bidx & 15) * 32;
        int r = tid >> 3, c4 = (tid & 7) * 4;
        float4 v = *(const float4*)&Wq[(k0 + r) * 512 + n0 + c4];
        sh[(c4 + 0) * 33 + r] = v.x;
        sh[(c4 + 1) * 33 + r] = v.y;
        sh[(c4 + 2) * 33 + r] = v.z;
        sh[(c4 + 3) * 33 + r] = v.w;
        __syncthreads();
        float w0 = sh[r * 33 + c4 + 0], w1 = sh[r * 33 + c4 + 1];
        float w2 = sh[r * 33 + c4 + 2], w3 = sh[r * 33 + c4 + 3];
        uint2 o;
        o.x = f2b(w0) | (f2b(w1) << 16);
        o.y = f2b(w2) | (f2b(w3) << 16);
        *(uint2*)&Wqt[(n0 + r) * 512 + k0 + c4] = o;
    } else {
        int h = blk - 1280;
        int rr = tid >> 6, c = tid & 63;
        float acc = 0.f;
        for (int j = 0; j < 128; ++j) {
            int d = rr + 4 * j;
            acc = fmaf(Wq[d * 512 + h * 64 + c], Wv[d], acc);
        }
        sh[rr * 64 + c] = acc;
        __syncthreads();
        if (rr == 0)
            t_out[h * 64 + c] = sh[c] + sh[64 + c] + sh[128 + c] + sh[192 + c];
    }
}

// ---- Qh = Xh @ Wq via MFMA; epilogue computes n, y, nmax ----
__global__ __launch_bounds__(256) void gemm_k(const unsigned short* __restrict__ Xh,
                                              const unsigned short* __restrict__ Wqt,
                                              const float* __restrict__ t_in,
                                              unsigned short* __restrict__ Qh,
                                              float* __restrict__ n_out,
                                              float* __restrict__ y_out,
                                              float* __restrict__ nmax) {
    __shared__ __align__(16) unsigned short As[64 * 64];
    __shared__ __align__(16) unsigned short Bs[64 * 64];
    int tid = threadIdx.x;
    int h = blockIdx.x;
    int m0 = blockIdx.y * 64, n0 = h * 64;
    int w = tid >> 6, lane = tid & 63;
    int tt = lane & 15, quad = lane >> 4;
    int srow = lane >> 3;
    int schunk = ((lane & 7) ^ srow) * 8;
    int arow = w * 16 + tt;
    f32x4 acc[4] = {{0.f,0.f,0.f,0.f},{0.f,0.f,0.f,0.f},{0.f,0.f,0.f,0.f},{0.f,0.f,0.f,0.f}};
    for (int k0 = 0; k0 < 512; k0 += 64) {
        __syncthreads();
        #pragma unroll
        for (int q = 0; q < 2; ++q) {
            int r0 = w * 16 + q * 8;
            glds16(&Xh[(m0 + r0 + srow) * 512 + k0 + schunk], &As[r0 * 64]);
            glds16(&Wqt[(n0 + r0 + srow) * 512 + k0 + schunk], &Bs[r0 * 64]);
        }
        __syncthreads();
        bf16x8 a0 = *(const bf16x8*)&As[SWZ(arow, quad)];
        bf16x8 a1 = *(const bf16x8*)&As[SWZ(arow, quad + 4)];
        #pragma unroll
        for (int ct = 0; ct < 4; ++ct) {
            int brow = ct * 16 + tt;
            bf16x8 b0 = *(const bf16x8*)&Bs[SWZ(brow, quad)];
            bf16x8 b1 = *(const bf16x8*)&Bs[SWZ(brow, quad + 4)];
            acc[ct] = __builtin_amdgcn_mfma_f32_16x16x32_bf16(a0, b0, acc[ct], 0, 0, 0);
            acc[ct] = __builtin_amdgcn_mfma_f32_16x16x32_bf16(a1, b1, acc[ct], 0, 0, 0);
        }
    }
    float tv[4];
    #pragma unroll
    for (int ct = 0; ct < 4; ++ct) tv[ct] = t_in[h * 64 + ct * 16 + tt];
    float s2[4] = {0.f,0.f,0.f,0.f}, yp[4] = {0.f,0.f,0.f,0.f};
    #pragma unroll
    for (int ct = 0; ct < 4; ++ct)
        #pragma unroll
        for (int g = 0; g < 4; ++g) {
            float v = acc[ct][g];
            s2[g] = fmaf(v, v, s2[g]);
            yp[g] = fmaf(v, tv[ct], yp[g]);
            Qh[(m0 + w * 16 + quad * 4 + g) * 512 + n0 + ct * 16 + tt] =
                (unsigned short)f2b(v);
        }
    #pragma unroll
    for (int off = 1; off <= 8; off <<= 1)
        #pragma unroll
        for (int g = 0; g < 4; ++g) {
            s2[g] += __shfl_xor(s2[g], off);
            yp[g] += __shfl_xor(yp[g], off);
        }
    float nv[4], nloc = 0.f;
    #pragma unroll
    for (int g = 0; g < 4; ++g) {
        nv[g] = sqrtf(s2[g]);
        nloc = fmaxf(nloc, nv[g]);
    }
    int bb = m0 >> 11;
    if (tt == 0) {
        #pragma unroll
        for (int g = 0; g < 4; ++g) {
            int row = m0 + w * 16 + quad * 4 + g;
            int idx = ((bb * 8 + h) << 11) + (row & 2047);
            n_out[idx] = nv[g];
            y_out[idx] = yp[g];
        }
    }
    #pragma unroll
    for (int off = 1; off <= 32; off <<= 1)
        nloc = fmaxf(nloc, __shfl_xor(nloc, off));
    if (lane == 0)
        atomicMax((int*)&nmax[bb * 8 + h], __float_as_int(nloc));
}

// ---- attention: 64 q-rows/block, 8 waves; wave (rg,cg) owns rows rg*16..+16,
//      t-column half cg. t-chunks of 128. ----
// arg = 0.25*LOG2E*dots + rowc[s] + tq[t];  rowc = -0.125*LOG2E*N*(2 n_s - 1)
__global__ __launch_bounds__(512) void attn_k(const unsigned short* __restrict__ Qh,
                                              const float* __restrict__ n_in,
                                              const float* __restrict__ y_in,
                                              const float* __restrict__ nmax,
                                              float* __restrict__ out) {
    __shared__ __align__(16) unsigned short QsL[64 * 64];
    __shared__ __align__(16) unsigned short QtL[128 * 64];
    __shared__ float rowcL[64];
    __shared__ float tqL[128], ytL[128];
    __shared__ float redN[2][64], redD[2][64];

    int tid = threadIdx.x;
    int bh = blockIdx.x >> 5;          // 16 bh x 32 tiles
    int tile = blockIdx.x & 31;
    int s0 = tile * 64;
    int b = bh >> 3, h = bh & 7;
    int rowbase = (b * 2048) * 512 + h * 64;
    int w = tid >> 6, lane = tid & 63;
    int rg = w >> 1, cg = w & 1;
    int tt = lane & 15, quad = lane >> 4;
    int srow = lane >> 3;
    int schunk = ((lane & 7) ^ srow) * 8;

    {
        int r0 = w * 8;                // 8 waves x 8 rows = 64
        glds16(&Qh[rowbase + (s0 + r0 + srow) * 512 + schunk], &QsL[r0 * 64]);
    }
    float Nv = nmax[bh];
    if (tid < 64) {
        float ns = n_in[bh * 2048 + s0 + tid];
        rowcL[tid] = -0.125f * LOG2E * Nv * (2.f * ns - 1.f);
    }
    __syncthreads();

    int arow = rg * 16 + tt;
    bf16x8 a0 = *(const bf16x8*)&QsL[SWZ(arow, quad)];
    bf16x8 a1 = *(const bf16x8*)&QsL[SWZ(arow, quad + 4)];
    float rc[4];
    #pragma unroll
    for (int g = 0; g < 4; ++g) rc[g] = rowcL[rg * 16 + quad * 4 + g];
    f32x4 num = {0.f, 0.f, 0.f, 0.f}, den = {0.f, 0.f, 0.f, 0.f};

    for (int t0 = 0; t0 < 2048; t0 += 128) {
        __syncthreads();
        #pragma unroll
        for (int q = 0; q < 2; ++q) {
            int r0 = w * 16 + q * 8;   // 8 waves x 16 rows = 128
            glds16(&Qh[rowbase + (t0 + r0 + srow) * 512 + schunk], &QtL[r0 * 64]);
        }
        if (tid < 128)
            tqL[tid] = -0.125f * LOG2E * n_in[bh * 2048 + t0 + tid];
        else if (tid < 256)
            ytL[tid - 128] = y_in[bh * 2048 + t0 + tid - 128];
        __syncthreads();

        #pragma unroll
        for (int j = 0; j < 4; ++j) {
            int trow = (cg * 4 + j) * 16 + tt;
            bf16x8 b0 = *(const bf16x8*)&QtL[SWZ(trow, quad)];
            bf16x8 b1 = *(const bf16x8*)&QtL[SWZ(trow, quad + 4)];
            f32x4 dot = {0.f, 0.f, 0.f, 0.f};
            dot = __builtin_amdgcn_mfma_f32_16x16x32_bf16(a0, b0, dot, 0, 0, 0);
            dot = __builtin_amdgcn_mfma_f32_16x16x32_bf16(a1, b1, dot, 0, 0, 0);
            float tqv = tqL[trow], yv = ytL[trow];
            #pragma unroll
            for (int g = 0; g < 4; ++g) {
                float arg = fmaf(0.25f * LOG2E, dot[g], rc[g] + tqv);
                float e = EXP2F(arg);
                num[g] = fmaf(e, yv, num[g]);
                den[g] += e;
            }
        }
    }

    #pragma unroll
    for (int off = 1; off <= 8; off <<= 1)
        #pragma unroll
        for (int g = 0; g < 4; ++g) {
            num[g] += __shfl_xor(num[g], off);
            den[g] += __shfl_xor(den[g], off);
        }
    if (tt == 0) {
        #pragma unroll
        for (int g = 0; g < 4; ++g) {
            redN[cg][rg * 16 + quad * 4 + g] = num[g];
            redD[cg][rg * 16 + quad * 4 + g] = den[g];
        }
    }
    __syncthreads();
    if (tid < 64) {
        float xn = redN[0][tid] + redN[1][tid];
        float xd = redD[0][tid] + redD[1][tid];
        float x = xn / xd;
        out[bh * 2048 + s0 + tid] = 1.0f / (1.0f + EXP2F(-x * LOG2E));
    }
}

extern "C" void kernel_launch(void* const* d_in, const int* in_sizes, int n_in,
                              void* d_out, int out_size, void* d_ws, size_t ws_size,
                              hipStream_t stream) {
    const float* X  = (const float*)d_in[0];
    const float* Wq = (const float*)d_in[1];
    const float* Wv = (const float*)d_in[2];
    float* out = (float*)d_out;
    float* ws = (float*)d_ws;

    float* t_ws    = ws;                  // 512
    float* n_ws    = ws + 512;            // 32768
    float* y_ws    = ws + 33280;          // 32768
    float* nmax_ws = ws + 66048;          // 16
    unsigned short* Qh_ws  = (unsigned short*)(ws + 66064);   // 2M bf16
    unsigned short* Xh_ws  = Qh_ws + 2097152;                 // 2M bf16
    unsigned short* Wqt_ws = Xh_ws + 2097152;                 // 256K bf16

    prep_k<<<1288, 256, 0, stream>>>(X, Wq, Wv, Xh_ws, Wqt_ws, t_ws);
    gemm_k<<<dim3(8, 64), 256, 0, stream>>>(Xh_ws, Wqt_ws, t_ws, Qh_ws,
                                            n_ws, y_ws, nmax_ws);
    attn_k<<<512, 512, 0, stream>>>(Qh_ws, n_ws, y_ws, nmax_ws, out);
}